// Round 9
// baseline (141.999 us; speedup 1.0000x reference)
//
#include <hip/hip_runtime.h>

// Encoder: per-atom top-T nearest grid points -> sum_t rbf[33] (x) (sh[9]*n*w)
// R8 lesson: per-dispatch fixed cost dominates (4KB fill node = 39us) ->
// minimize kernel count. 4 dispatches:
// K1 hist_store: ONE full scan; per-slice LDS hist of in-cutoff d2 bits
//                (plain-stored, no pre-zero needed) + (bits,idx) pair append
// K2 thresh    : per-atom block: sum slice hists -> b1 (2-level parallel
//                scan, no serial walks), fine-hist own pairs in bin b1,
//                scan again -> exact 32-ULP rank-T threshold
// K3 accum     : filter pairs by thr[a], bf16 MFMA, cross-wave LDS reduce,
//                one plain 297-float store per block (no output atomics)
// K4 reduce    : sum 64 chunk-partials per atom -> out (plain stores)

typedef float f32x4 __attribute__((ext_vector_type(4)));
typedef int   i32x4 __attribute__((ext_vector_type(4)));

#define SLICES 16
#define HBINS  8192
#define CHA    4             // accum chunks per segment
#define NCHUNK (SLICES * CHA)
#define PBSTR  304           // partials row stride (297 rounded up, 16B mult)
#define CUT25  0x41C80000u   // __float_as_uint(25.0f) == CUTOFF^2 bits

__device__ __forceinline__ unsigned d2bits(float px, float py, float pz,
                                           float gx, float gy, float gz) {
  float dx = px - gx, dy = py - gy, dz = pz - gz;
  float d2 = __fmaf_rn(dx, dx, __fmaf_rn(dy, dy, __fmul_rn(dz, dz)));
  return __float_as_uint(d2);
}

__device__ __forceinline__ unsigned short tobf(float v) {
  return (unsigned short)((__float_as_uint(v) + 0x8000u) >> 16);
}

__device__ __forceinline__ void mfma_acc(f32x4& d, i32x4 a, i32x4 b) {
  asm("v_mfma_f32_16x16x32_bf16 %0, %1, %2, %0" : "+v"(d) : "v"(a), "v"(b));
}

// First wave finds the bin where cumulative count crosses rank R.
// Two-level parallel scan: level A = 64 lanes x 128-bin sums + prefix;
// level B = 64 lanes x 2 bins of the crossing range + prefix; <=2 serial.
// Caller pre-inits *o_bin = HBINS-1, *o_pre = 0 (no-crossing defaults)
// and __syncthreads() after.
__device__ __forceinline__ void scan_find(const unsigned* hist, unsigned R,
                                          unsigned* o_bin, unsigned* o_pre) {
  if (threadIdx.x < 64) {
    int lane = threadIdx.x;
    const int per = HBINS >> 6;            // 128
    int base = lane * per;
    unsigned ssum = 0;
    #pragma unroll 8
    for (int k = 0; k < per; ++k) ssum += hist[base + k];
    unsigned p = ssum;
    #pragma unroll
    for (int d = 1; d < 64; d <<= 1) {
      unsigned t = __shfl_up(p, d);
      if (lane >= d) p += t;
    }
    unsigned excl = p - ssum;
    unsigned long long mask = __ballot(excl < R && R <= p);
    if (mask) {                            // uniform across wave
      int cl = (int)(__ffsll((unsigned long long)mask) - 1);
      unsigned excl_cl = __shfl(excl, cl);
      unsigned Rp = R - excl_cl;           // rank within crossing range
      int b2 = cl * per + 2 * lane;        // 64 lanes x 2 bins = 128
      unsigned h0 = hist[b2], h1 = hist[b2 + 1];
      unsigned ss2 = h0 + h1;
      unsigned p2 = ss2;
      #pragma unroll
      for (int d = 1; d < 64; d <<= 1) {
        unsigned t = __shfl_up(p2, d);
        if (lane >= d) p2 += t;
      }
      unsigned excl2 = p2 - ss2;
      if (excl2 < Rp && Rp <= p2) {        // unique crossing lane
        if (excl2 + h0 >= Rp) { *o_bin = (unsigned)b2;     *o_pre = excl_cl + excl2; }
        else                  { *o_bin = (unsigned)(b2+1); *o_pre = excl_cl + excl2 + h0; }
      }
    }
  }
}

// ---------------- K1: full scan -> per-slice hist (plain store) + pairs ----------------
__global__ __launch_bounds__(256) void enc_hist_store(
    const float* __restrict__ nuc, const float* __restrict__ grid, int N,
    unsigned* __restrict__ hists, unsigned* __restrict__ cnt,
    uint2* __restrict__ pairs, int scap) {
  __shared__ unsigned lh[HBINS];
  __shared__ unsigned s_cnt;
  int a = blockIdx.x / SLICES, s = blockIdx.x % SLICES;
  for (int t = threadIdx.x; t < HBINS; t += 256) lh[t] = 0;
  if (threadIdx.x == 0) s_cnt = 0;
  __syncthreads();

  float px = nuc[3*a+0], py = nuc[3*a+1], pz = nuc[3*a+2];
  int per = (N + SLICES - 1) / SLICES;
  int lo = s * per, hi = min(N, lo + per);
  int lane = threadIdx.x & 63;
  uint2* seg = pairs + (size_t)blockIdx.x * scap;

  for (int i = lo + threadIdx.x; i < hi; i += 256) {
    float gx = grid[3*i+0], gy = grid[3*i+1], gz = grid[3*i+2];
    unsigned bits = d2bits(px, py, pz, gx, gy, gz);
    bool sel = bits < CUT25;                      // envelope != 0 only here
    if (sel) atomicAdd(&lh[bits >> 18], 1u);
    unsigned long long mm = __ballot(sel);
    if (mm) {
      int leader = __ffsll(mm) - 1;
      unsigned base = 0;
      if (lane == leader) base = atomicAdd(&s_cnt, (unsigned)__popcll(mm));
      base = __shfl(base, leader);
      if (sel) {
        unsigned pos = base + (unsigned)__popcll(mm & ((1ull << lane) - 1ull));
        if (pos < (unsigned)scap) seg[pos] = make_uint2(bits, (unsigned)i);
      }
    }
  }
  __syncthreads();
  i32x4* gh = (i32x4*)(hists + (size_t)blockIdx.x * HBINS);
  const i32x4* lv = (const i32x4*)lh;
  for (int t = threadIdx.x; t < HBINS / 4; t += 256) gh[t] = lv[t];  // plain store
  if (threadIdx.x == 0) cnt[blockIdx.x] = s_cnt;
}

// ---------------- K2: per-atom threshold (coarse scan + fine hist + scan) ----------------
__global__ __launch_bounds__(256) void enc_thresh(
    const unsigned* __restrict__ hists, const unsigned* __restrict__ cnt,
    const uint2* __restrict__ pairs, int scap, unsigned T,
    unsigned* __restrict__ thr) {
  __shared__ unsigned lh[HBINS];
  __shared__ unsigned s_bin, s_pre;
  int a = blockIdx.x;

  // (a) sum the atom's SLICES per-slice hists into LDS
  const i32x4* base = (const i32x4*)(hists + (size_t)a * SLICES * HBINS);
  for (int t = threadIdx.x; t < HBINS / 4; t += 256) {
    i32x4 acc = base[t];
    #pragma unroll
    for (int s = 1; s < SLICES; ++s) acc += base[(size_t)s * (HBINS / 4) + t];
    ((i32x4*)lh)[t] = acc;
  }
  if (threadIdx.x == 0) { s_bin = HBINS - 1; s_pre = 0; }
  __syncthreads();
  scan_find(lh, T, &s_bin, &s_pre);
  __syncthreads();
  unsigned b1 = s_bin, R2 = T - s_pre;   // if no crossing: b1=8191 (empty), R2=T
  __syncthreads();

  // (b) re-zero; (c) fine hist of this atom's pairs in crossing bin b1
  i32x4 z = {0, 0, 0, 0};
  for (int t = threadIdx.x; t < HBINS / 4; t += 256) ((i32x4*)lh)[t] = z;
  if (threadIdx.x == 0) { s_bin = HBINS - 1; s_pre = 0; }
  __syncthreads();
  for (int s = 0; s < SLICES; ++s) {
    int seg_id = a * SLICES + s;
    int tot = min((int)cnt[seg_id], scap);
    const uint2* seg = pairs + (size_t)seg_id * scap;
    for (int i = threadIdx.x; i < tot; i += 256) {
      uint2 p = seg[i];
      if ((p.x >> 18) == b1) atomicAdd(&lh[(p.x >> 5) & (HBINS - 1)], 1u);
    }
  }
  __syncthreads();
  scan_find(lh, R2, &s_bin, &s_pre);
  __syncthreads();
  if (threadIdx.x == 0) thr[a] = (b1 << 13) | s_bin;  // select (bits>>5) <= thr
}

// ---------------- K3: MFMA accumulation -> per-block partials (no atomics) ----------------
__global__ __launch_bounds__(256, 4) void enc_accum(
    const float* __restrict__ nuc, const float* __restrict__ grid,
    const float* __restrict__ wv, const float* __restrict__ nv,
    const unsigned* __restrict__ thrv, const unsigned* __restrict__ cnt,
    const uint2* __restrict__ pairs, int scap, float* __restrict__ pb) {
  __shared__ __align__(16) unsigned short lds[4][4608];  // per-wave 3456 A + 1152 B
  int seg_id = blockIdx.x / CHA, c = blockIdx.x % CHA;
  int a = seg_id / SLICES;
  int tid = threadIdx.x, lane = tid & 63, w = tid >> 6;
  unsigned short* SB = &lds[w][0];

  { // zero this wave's LDS region (covers A pad rows 33..47, B rows 9..15)
    i32x4 z = {0, 0, 0, 0};
    i32x4* zp = (i32x4*)SB;
    #pragma unroll
    for (int t = 0; t < 9; ++t) zp[lane + t * 64] = z;
  }

  unsigned thr = thrv[a];
  float px = nuc[3*a+0], py = nuc[3*a+1], pz = nuc[3*a+2];
  int total = min((int)cnt[seg_id], scap);
  const uint2* lst = pairs + (size_t)seg_id * scap;

  f32x4 acc0 = {0,0,0,0}, acc1 = {0,0,0,0}, acc2 = {0,0,0,0};
  int m = lane & 15, q = lane >> 4;
  const float SQRT2 = 1.41421356237309515f;
  const float PIF   = 3.14159265358979323846f;
  const float S3    = 1.73205080756887729f;

  for (int jb = c * 256 + w * 64; jb < total; jb += CHA * 256) {
    int j = jb + lane;
    bool valid = j < total;
    uint2 pr = valid ? lst[j] : make_uint2(0xFFFFFFFFu, 0u);
    bool live = valid && ((pr.x >> 5) <= thr);   // stored => d2 < 25 => rn < 1
    unsigned gi = pr.y;
    if (live) {
      float gx = grid[3*gi+0], gy = grid[3*gi+1], gz = grid[3*gi+2];
      float dx = px - gx, dy = py - gy, dz = pz - gz;
      float d2 = __fmaf_rn(dx, dx, __fmaf_rn(dy, dy, dz * dz));
#if __has_builtin(__builtin_amdgcn_sqrtf)
      float rn = __builtin_amdgcn_sqrtf(d2) * 0.2f;
#else
      float rn = sqrtf(d2) * 0.2f;
#endif
      float x2 = rn * rn;
      float x6 = x2 * x2 * x2;
      float e  = __fmaf_rn(x6, __fmaf_rn(-21.f, x2, __fmaf_rn(48.f, rn, -28.f)), 1.f);
      float f  = SQRT2 * e;
      float nw = nv[gi] * wv[gi];
#if __has_builtin(__builtin_amdgcn_rcpf)
      float inv = 0.2f * __builtin_amdgcn_rcpf(rn + 1e-15f);
#else
      float inv = 0.2f / (rn + 1e-15f);
#endif
      float X = dx * inv, Y = dy * inv, Z = dz * inv;
      float r2 = __fmaf_rn(X, X, __fmaf_rn(Y, Y, Z * Z));
      // B rows: v[h] = nw * sh[h]
      SB[3456 + 0*72 + lane] = tobf(nw);
      SB[3456 + 1*72 + lane] = tobf(nw * Y);
      SB[3456 + 2*72 + lane] = tobf(nw * Z);
      SB[3456 + 3*72 + lane] = tobf(nw * X);
      SB[3456 + 4*72 + lane] = tobf(nw * S3 * X * Y);
      SB[3456 + 5*72 + lane] = tobf(nw * S3 * Y * Z);
      SB[3456 + 6*72 + lane] = tobf(nw * 0.5f * __fmaf_rn(3.f, Z * Z, -r2));
      SB[3456 + 7*72 + lane] = tobf(nw * S3 * X * Z);
      SB[3456 + 8*72 + lane] = tobf(nw * 0.5f * S3 * (X * X - Y * Y));
      // A rows: rbf[r] = sqrt2*e*[0.1, sin(k pi r), cos(k pi r)]
      float s1 = __sinf(PIF * rn), c1 = __cosf(PIF * rn);
      SB[0 * 72 + lane]  = tobf(0.1f * f);
      float sk = s1, ck = c1;
      SB[1 * 72 + lane]  = tobf(f * sk);
      SB[17 * 72 + lane] = tobf(f * ck);
      #pragma unroll
      for (int k = 2; k <= 16; ++k) {
        float sn = __fmaf_rn(sk, c1, ck * s1);
        float cn = __fmaf_rn(ck, c1, -(sk * s1));
        sk = sn; ck = cn;
        SB[k * 72 + lane]        = tobf(f * sk);
        SB[(16 + k) * 72 + lane] = tobf(f * ck);
      }
    } else {
      // zero B column -> this point contributes nothing (A may be stale)
      #pragma unroll
      for (int h = 0; h < 9; ++h) SB[3456 + h * 72 + lane] = 0;
    }
    // MFMA: A[m=r][k=p], B[k=p][n=h]; lane m=l&15, k=8*(l>>4)+j (+32 per k-group)
    #pragma unroll
    for (int g = 0; g < 2; ++g) {
      int cb = 8 * q + 32 * g;
      i32x4 bf = *(const i32x4*)&SB[3456 + m * 72 + cb];
      i32x4 a0 = *(const i32x4*)&SB[(0  + m) * 72 + cb];
      mfma_acc(acc0, a0, bf);
      i32x4 a1 = *(const i32x4*)&SB[(16 + m) * 72 + cb];
      mfma_acc(acc1, a1, bf);
      i32x4 a2 = *(const i32x4*)&SB[(32 + m) * 72 + cb];
      mfma_acc(acc2, a2, bf);
    }
  }
  // MFMA -> VALU read hazard guard
  asm volatile("s_nop 7\n\ts_nop 7" : "+v"(acc0), "+v"(acc1), "+v"(acc2));

  // cross-wave reduction in LDS (wave-private regions)
  float* redw = (float*)&lds[w][0];
  if (m < 9) {
    #pragma unroll
    for (int t = 0; t < 4; ++t) {
      int row = 4 * q + t;                 // C/D: col=lane&15, row=(lane>>4)*4+t
      redw[(row +  0) * 9 + m] = acc0[t];
      redw[(row + 16) * 9 + m] = acc1[t];
      if (row + 32 < 33) redw[(row + 32) * 9 + m] = acc2[t];
    }
  }
  __syncthreads();
  float* pbb = pb + (size_t)blockIdx.x * PBSTR;
  for (int v = tid; v < 297; v += 256) {
    float s0 = ((const float*)&lds[0][0])[v] + ((const float*)&lds[1][0])[v];
    float s1 = ((const float*)&lds[2][0])[v] + ((const float*)&lds[3][0])[v];
    pbb[v] = s0 + s1;                      // plain store -- zero atomics
  }
}

// ---------------- K4: sum chunk partials -> out ----------------
__global__ __launch_bounds__(256) void enc_reduce(
    const float* __restrict__ pb, float* __restrict__ out, int nout) {
  int idx = blockIdx.x * 256 + threadIdx.x;
  if (idx >= nout) return;
  int a = idx / 297, v = idx - a * 297;
  const float* p = pb + (size_t)a * NCHUNK * PBSTR + v;
  float s = 0.f;
  #pragma unroll 8
  for (int k = 0; k < NCHUNK; ++k) s += p[(size_t)k * PBSTR];
  out[idx] = s;
}

extern "C" void kernel_launch(void* const* d_in, const int* in_sizes, int n_in,
                              void* d_out, int out_size, void* d_ws, size_t ws_size,
                              hipStream_t stream) {
  const float* nuc  = (const float*)d_in[0];
  // d_in[1] = atom_mask (unused by reference math)
  const float* grid = (const float*)d_in[2];
  const float* wts  = (const float*)d_in[3];
  const float* nn   = (const float*)d_in[4];
  int A = in_sizes[0] / 3;
  int N = in_sizes[2] / 3;
  long long t8 = (8LL * (long long)N) / (long long)A;
  unsigned T = (unsigned)(t8 < (long long)N ? t8 : (long long)N);

  // ws: [cnt A*SLICES][thr A][hists A*SLICES*HBINS]
  //     [pb A*SLICES*CHA*PBSTR floats][pairs uint2 ...]
  unsigned* ws    = (unsigned*)d_ws;
  unsigned* cnt   = ws;
  unsigned* thr   = cnt + A * SLICES;
  unsigned* hists = thr + A;
  float*    pb    = (float*)(hists + (size_t)A * SLICES * HBINS);
  uint2*    pairs = (uint2*)(pb + (size_t)A * SLICES * CHA * PBSTR);

  // per-slice scan range bounds the stored count -> overflow impossible
  int SCAP = (N + SLICES - 1) / SLICES;
  {
    long long head  = (long long)(((unsigned*)pairs) - ws);    // dwords
    long long avail = (long long)(ws_size / 4) - head;         // dwords
    long long need  = 2LL * SCAP * A * SLICES;                 // uint2 = 2 dwords
    if (avail > 0 && need > avail) SCAP = (int)(avail / (2LL * A * SLICES));
  }
  float* out = (float*)d_out;
  int nout = A * 297;

  enc_hist_store<<<A * SLICES,         256, 0, stream>>>(nuc, grid, N, hists, cnt,
                                                         pairs, SCAP);
  enc_thresh    <<<A,                  256, 0, stream>>>(hists, cnt, pairs, SCAP, T, thr);
  enc_accum     <<<A * SLICES * CHA,   256, 0, stream>>>(nuc, grid, wts, nn, thr, cnt,
                                                         pairs, SCAP, pb);
  enc_reduce    <<<(nout + 255) / 256, 256, 0, stream>>>(pb, out, nout);
}

// Round 10
// 66.578 us; speedup vs baseline: 2.1328x; 2.1328x over previous
//
#include <hip/hip_runtime.h>

// Encoder: per-atom top-T nearest grid points -> sum_t rbf[33] (x) (sh[9]*n*w)
// R9 lesson: 64-block kernels must read TINY data (latency-bound at 1 wave/SIMD).
// R8-split structure, slimmed:
// K1 hist_store: full scan (float4 loads); 256-bin clamped coarse hist of
//                in-cutoff d2 bits (LDS 1KB, plain-stored); (bits,idx) pair
//                append; zeroes its ghist2 stripe (no zero kernel)
// K2 scan1     : per-atom: sum 16x256-bin hists (16KB), find b1 + residual R2
// K3 fine      : chunked; bin crossing-coarse-bin pairs into ghist2
// K4 scan2     : per-atom: LDS-stage 32KB fine hist, 2-level scan -> threshold
// K5 accum     : filter pairs by thr[a], bf16 MFMA, LDS cross-wave reduce,
//                one plain 297-float store per block (no output atomics)
// K6 reduce    : sum 64 chunk-partials per atom -> out

typedef float f32x4 __attribute__((ext_vector_type(4)));
typedef int   i32x4 __attribute__((ext_vector_type(4)));

#define SLICES 16
#define HBINS  8192          // fine bins
#define NB1    256           // coarse bins (clamped)
#define CLAMP0 4000u         // = 125<<5; bits>>18 below this (d2<0.25) -> bin 0
#define CHA    4             // accum chunks per segment
#define CHF    4             // fine chunks per segment
#define NCHUNK (SLICES * CHA)
#define PBSTR  304           // partials row stride
#define CUT25  0x41C80000u   // __float_as_uint(25.0f) == CUTOFF^2 bits

__device__ __forceinline__ unsigned d2bits(float px, float py, float pz,
                                           float gx, float gy, float gz) {
  float dx = px - gx, dy = py - gy, dz = pz - gz;
  float d2 = __fmaf_rn(dx, dx, __fmaf_rn(dy, dy, __fmul_rn(dz, dz)));
  return __float_as_uint(d2);
}

__device__ __forceinline__ unsigned short tobf(float v) {
  return (unsigned short)((__float_as_uint(v) + 0x8000u) >> 16);
}

__device__ __forceinline__ void mfma_acc(f32x4& d, i32x4 a, i32x4 b) {
  asm("v_mfma_f32_16x16x32_bf16 %0, %1, %2, %0" : "+v"(d) : "v"(a), "v"(b));
}

// ---------------- K1: full scan -> clamped coarse hist + pairs ----------------
__global__ __launch_bounds__(256) void enc_hist_store(
    const float* __restrict__ nuc, const float* __restrict__ grid, int N,
    unsigned* __restrict__ hists, unsigned* __restrict__ cnt,
    uint2* __restrict__ pairs, int scap, unsigned* __restrict__ ghist2) {
  __shared__ unsigned lh[NB1];
  __shared__ unsigned s_cnt;
  int a = blockIdx.x / SLICES, s = blockIdx.x % SLICES;
  int tid = threadIdx.x, lane = tid & 63;
  if (tid < NB1) lh[tid] = 0;
  if (tid == 0) s_cnt = 0;
  { // zero this block's stripe of atom a's fine hist (written by K3 later)
    const int stripe = HBINS / SLICES;     // 512
    unsigned* g2 = ghist2 + (size_t)a * HBINS + s * stripe;
    for (int t = tid; t < stripe; t += 256) g2[t] = 0;
  }
  __syncthreads();

  float px = nuc[3*a+0], py = nuc[3*a+1], pz = nuc[3*a+2];
  uint2* seg = pairs + (size_t)blockIdx.x * scap;
  const float4* G4 = (const float4*)grid;
  int nq = N >> 2;
  int qper = (nq + SLICES - 1) / SLICES;
  int qlo = s * qper, qhi = min(nq, qlo + qper);

  for (int qi = qlo + tid; qi < qhi; qi += 256) {
    float4 A4 = G4[3*qi], B4 = G4[3*qi+1], C4 = G4[3*qi+2];
    float xs[4] = {A4.x, A4.w, B4.z, C4.y};
    float ys[4] = {A4.y, B4.x, B4.w, C4.z};
    float zs[4] = {A4.z, B4.y, C4.x, C4.w};
    unsigned bt[4];
    #pragma unroll
    for (int k = 0; k < 4; ++k) {
      bt[k] = d2bits(px, py, pz, xs[k], ys[k], zs[k]);
      if (bt[k] < CUT25) {
        int cb = (int)(bt[k] >> 18) - (int)CLAMP0;
        atomicAdd(&lh[cb > 0 ? cb : 0], 1u);
      }
    }
    #pragma unroll
    for (int k = 0; k < 4; ++k) {
      bool sel = bt[k] < CUT25;
      unsigned long long mm = __ballot(sel);
      if (mm) {
        int leader = __ffsll(mm) - 1;
        unsigned base = 0;
        if (lane == leader) base = atomicAdd(&s_cnt, (unsigned)__popcll(mm));
        base = __shfl(base, leader);
        if (sel) {
          unsigned pos = base + (unsigned)__popcll(mm & ((1ull << lane) - 1ull));
          if (pos < (unsigned)scap) seg[pos] = make_uint2(bt[k], (unsigned)(4*qi + k));
        }
      }
    }
  }
  if (s == SLICES - 1) {                   // scalar tail (N % 4 points)
    for (int i = 4*nq + tid; i < N; i += 256) {
      unsigned bits = d2bits(px, py, pz, grid[3*i+0], grid[3*i+1], grid[3*i+2]);
      bool sel = bits < CUT25;
      if (sel) {
        int cb = (int)(bits >> 18) - (int)CLAMP0;
        atomicAdd(&lh[cb > 0 ? cb : 0], 1u);
      }
      unsigned long long mm = __ballot(sel);
      if (mm) {
        int leader = __ffsll(mm) - 1;
        unsigned base = 0;
        if (lane == leader) base = atomicAdd(&s_cnt, (unsigned)__popcll(mm));
        base = __shfl(base, leader);
        if (sel) {
          unsigned pos = base + (unsigned)__popcll(mm & ((1ull << lane) - 1ull));
          if (pos < (unsigned)scap) seg[pos] = make_uint2(bits, (unsigned)i);
        }
      }
    }
  }
  __syncthreads();
  if (tid < NB1) hists[(size_t)blockIdx.x * NB1 + tid] = lh[tid];  // plain store
  if (tid == 0) cnt[blockIdx.x] = s_cnt;
}

// ---------------- K2: per-atom coarse scan (16KB read) ----------------
__global__ __launch_bounds__(256) void enc_scan1(
    const unsigned* __restrict__ hists, unsigned T,
    unsigned* __restrict__ b1r, unsigned* __restrict__ r2r) {
  __shared__ unsigned lh[NB1];
  __shared__ unsigned s_bin, s_pre;
  int a = blockIdx.x, tid = threadIdx.x;
  if (tid < NB1) {
    unsigned acc = 0;
    const unsigned* base = hists + (size_t)a * SLICES * NB1 + tid;
    #pragma unroll
    for (int s = 0; s < SLICES; ++s) acc += base[(size_t)s * NB1];
    lh[tid] = acc;
  }
  if (tid == 0) { s_bin = NB1 - 1; s_pre = 0; }
  __syncthreads();
  if (tid < 64) {
    int lane = tid, base = 4 * lane;
    unsigned h0 = lh[base], h1 = lh[base+1], h2 = lh[base+2], h3 = lh[base+3];
    unsigned ssum = h0 + h1 + h2 + h3;
    unsigned p = ssum;
    #pragma unroll
    for (int d = 1; d < 64; d <<= 1) {
      unsigned t = __shfl_up(p, d);
      if (lane >= d) p += t;
    }
    unsigned excl = p - ssum;
    if (excl < T && T <= p) {              // unique crossing lane
      unsigned cum = excl;
      unsigned hh[4] = {h0, h1, h2, h3};
      #pragma unroll
      for (int k = 0; k < 4; ++k) {
        if (cum + hh[k] >= T) { s_bin = (unsigned)(base + k); s_pre = cum; break; }
        cum += hh[k];
      }
    }
  }
  __syncthreads();
  if (tid == 0) { b1r[a] = s_bin; r2r[a] = T - s_pre; }
}

// ---------------- K3: fine hist of crossing-bin pairs (chunked) ----------------
__global__ __launch_bounds__(256) void enc_fine(
    const unsigned* __restrict__ b1r, const unsigned* __restrict__ cnt,
    const uint2* __restrict__ pairs, int scap, unsigned* __restrict__ ghist2) {
  int seg_id = blockIdx.x / CHF, c = blockIdx.x % CHF;
  int a = seg_id / SLICES;
  unsigned b1c = b1r[a];
  unsigned tb1 = b1c + CLAMP0;
  int total = min((int)cnt[seg_id], scap);
  const uint2* seg = pairs + (size_t)seg_id * scap;
  unsigned* gh2 = ghist2 + (size_t)a * HBINS;
  for (int i = c * 256 + threadIdx.x; i < total; i += CHF * 256) {
    uint2 p = seg[i];
    unsigned cb = p.x >> 18;
    bool match = b1c ? (cb == tb1) : (cb <= CLAMP0);  // bin0 = clamped region
    if (match) atomicAdd(&gh2[(p.x >> 5) & (HBINS - 1)], 1u);
  }
}

// ---------------- K4: per-atom fine scan (LDS-staged, 2-level) ----------------
__global__ __launch_bounds__(256) void enc_scan2(
    const unsigned* __restrict__ ghist2, const unsigned* __restrict__ b1r,
    const unsigned* __restrict__ r2r, unsigned* __restrict__ thr) {
  __shared__ unsigned lh[HBINS];
  __shared__ unsigned s_bin, s_pre;
  int a = blockIdx.x, tid = threadIdx.x;
  const i32x4* gh = (const i32x4*)(ghist2 + (size_t)a * HBINS);
  for (int t = tid; t < HBINS / 4; t += 256) ((i32x4*)lh)[t] = gh[t];
  if (tid == 0) { s_bin = HBINS - 1; s_pre = 0; }
  __syncthreads();
  unsigned R = r2r[a];
  if (tid < 64) {
    int lane = tid;
    const int per = HBINS >> 6;            // 128
    int base = lane * per;
    unsigned ssum = 0;
    #pragma unroll 8
    for (int k = 0; k < per; ++k) ssum += lh[base + k];
    unsigned p = ssum;
    #pragma unroll
    for (int d = 1; d < 64; d <<= 1) {
      unsigned t = __shfl_up(p, d);
      if (lane >= d) p += t;
    }
    unsigned excl = p - ssum;
    unsigned long long mask = __ballot(excl < R && R <= p);
    if (mask) {
      int cl = (int)(__ffsll(mask) - 1);
      unsigned excl_cl = __shfl(excl, cl);
      unsigned Rp = R - excl_cl;
      int b2 = cl * per + 2 * lane;
      unsigned h0 = lh[b2], h1 = lh[b2 + 1];
      unsigned ss2 = h0 + h1;
      unsigned p2 = ss2;
      #pragma unroll
      for (int d = 1; d < 64; d <<= 1) {
        unsigned t = __shfl_up(p2, d);
        if (lane >= d) p2 += t;
      }
      unsigned excl2 = p2 - ss2;
      if (excl2 < Rp && Rp <= p2) {
        if (excl2 + h0 >= Rp) s_bin = (unsigned)b2;
        else                  s_bin = (unsigned)(b2 + 1);
      }
    }
  }
  __syncthreads();
  if (tid == 0) thr[a] = ((b1r[a] + CLAMP0) << 13) | s_bin;  // (bits>>5) <= thr
}

// ---------------- K5: MFMA accumulation -> per-block partials ----------------
__global__ __launch_bounds__(256, 4) void enc_accum(
    const float* __restrict__ nuc, const float* __restrict__ grid,
    const float* __restrict__ wv, const float* __restrict__ nv,
    const unsigned* __restrict__ thrv, const unsigned* __restrict__ cnt,
    const uint2* __restrict__ pairs, int scap, float* __restrict__ pb) {
  __shared__ __align__(16) unsigned short lds[4][4608];  // per-wave 3456 A + 1152 B
  int seg_id = blockIdx.x / CHA, c = blockIdx.x % CHA;
  int a = seg_id / SLICES;
  int tid = threadIdx.x, lane = tid & 63, w = tid >> 6;
  unsigned short* SB = &lds[w][0];

  { // zero this wave's LDS region (covers A pad rows 33..47, B rows 9..15)
    i32x4 z = {0, 0, 0, 0};
    i32x4* zp = (i32x4*)SB;
    #pragma unroll
    for (int t = 0; t < 9; ++t) zp[lane + t * 64] = z;
  }

  unsigned thr = thrv[a];
  float px = nuc[3*a+0], py = nuc[3*a+1], pz = nuc[3*a+2];
  int total = min((int)cnt[seg_id], scap);
  const uint2* lst = pairs + (size_t)seg_id * scap;

  f32x4 acc0 = {0,0,0,0}, acc1 = {0,0,0,0}, acc2 = {0,0,0,0};
  int m = lane & 15, q = lane >> 4;
  const float SQRT2 = 1.41421356237309515f;
  const float PIF   = 3.14159265358979323846f;
  const float S3    = 1.73205080756887729f;

  for (int jb = c * 256 + w * 64; jb < total; jb += CHA * 256) {
    int j = jb + lane;
    bool valid = j < total;
    uint2 pr = valid ? lst[j] : make_uint2(0xFFFFFFFFu, 0u);
    bool live = valid && ((pr.x >> 5) <= thr);   // stored => d2 < 25 => rn < 1
    unsigned gi = pr.y;
    if (live) {
      float gx = grid[3*gi+0], gy = grid[3*gi+1], gz = grid[3*gi+2];
      float dx = px - gx, dy = py - gy, dz = pz - gz;
      float d2 = __fmaf_rn(dx, dx, __fmaf_rn(dy, dy, dz * dz));
#if __has_builtin(__builtin_amdgcn_sqrtf)
      float rn = __builtin_amdgcn_sqrtf(d2) * 0.2f;
#else
      float rn = sqrtf(d2) * 0.2f;
#endif
      float x2 = rn * rn;
      float x6 = x2 * x2 * x2;
      float e  = __fmaf_rn(x6, __fmaf_rn(-21.f, x2, __fmaf_rn(48.f, rn, -28.f)), 1.f);
      float f  = SQRT2 * e;
      float nw = nv[gi] * wv[gi];
#if __has_builtin(__builtin_amdgcn_rcpf)
      float inv = 0.2f * __builtin_amdgcn_rcpf(rn + 1e-15f);
#else
      float inv = 0.2f / (rn + 1e-15f);
#endif
      float X = dx * inv, Y = dy * inv, Z = dz * inv;
      float r2 = __fmaf_rn(X, X, __fmaf_rn(Y, Y, Z * Z));
      // B rows: v[h] = nw * sh[h]
      SB[3456 + 0*72 + lane] = tobf(nw);
      SB[3456 + 1*72 + lane] = tobf(nw * Y);
      SB[3456 + 2*72 + lane] = tobf(nw * Z);
      SB[3456 + 3*72 + lane] = tobf(nw * X);
      SB[3456 + 4*72 + lane] = tobf(nw * S3 * X * Y);
      SB[3456 + 5*72 + lane] = tobf(nw * S3 * Y * Z);
      SB[3456 + 6*72 + lane] = tobf(nw * 0.5f * __fmaf_rn(3.f, Z * Z, -r2));
      SB[3456 + 7*72 + lane] = tobf(nw * S3 * X * Z);
      SB[3456 + 8*72 + lane] = tobf(nw * 0.5f * S3 * (X * X - Y * Y));
      // A rows: rbf[r] = sqrt2*e*[0.1, sin(k pi r), cos(k pi r)]
      float s1 = __sinf(PIF * rn), c1 = __cosf(PIF * rn);
      SB[0 * 72 + lane]  = tobf(0.1f * f);
      float sk = s1, ck = c1;
      SB[1 * 72 + lane]  = tobf(f * sk);
      SB[17 * 72 + lane] = tobf(f * ck);
      #pragma unroll
      for (int k = 2; k <= 16; ++k) {
        float sn = __fmaf_rn(sk, c1, ck * s1);
        float cn = __fmaf_rn(ck, c1, -(sk * s1));
        sk = sn; ck = cn;
        SB[k * 72 + lane]        = tobf(f * sk);
        SB[(16 + k) * 72 + lane] = tobf(f * ck);
      }
    } else {
      // zero B column -> this point contributes nothing (A may be stale)
      #pragma unroll
      for (int h = 0; h < 9; ++h) SB[3456 + h * 72 + lane] = 0;
    }
    // MFMA: A[m=r][k=p], B[k=p][n=h]; lane m=l&15, k=8*(l>>4)+j (+32 per k-group)
    #pragma unroll
    for (int g = 0; g < 2; ++g) {
      int cb = 8 * q + 32 * g;
      i32x4 bf = *(const i32x4*)&SB[3456 + m * 72 + cb];
      i32x4 a0 = *(const i32x4*)&SB[(0  + m) * 72 + cb];
      mfma_acc(acc0, a0, bf);
      i32x4 a1 = *(const i32x4*)&SB[(16 + m) * 72 + cb];
      mfma_acc(acc1, a1, bf);
      i32x4 a2 = *(const i32x4*)&SB[(32 + m) * 72 + cb];
      mfma_acc(acc2, a2, bf);
    }
  }
  // MFMA -> VALU read hazard guard
  asm volatile("s_nop 7\n\ts_nop 7" : "+v"(acc0), "+v"(acc1), "+v"(acc2));

  // cross-wave reduction in LDS (wave-private regions)
  float* redw = (float*)&lds[w][0];
  if (m < 9) {
    #pragma unroll
    for (int t = 0; t < 4; ++t) {
      int row = 4 * q + t;                 // C/D: col=lane&15, row=(lane>>4)*4+t
      redw[(row +  0) * 9 + m] = acc0[t];
      redw[(row + 16) * 9 + m] = acc1[t];
      if (row + 32 < 33) redw[(row + 32) * 9 + m] = acc2[t];
    }
  }
  __syncthreads();
  float* pbb = pb + (size_t)blockIdx.x * PBSTR;
  for (int v = tid; v < 297; v += 256) {
    float s0 = ((const float*)&lds[0][0])[v] + ((const float*)&lds[1][0])[v];
    float s1 = ((const float*)&lds[2][0])[v] + ((const float*)&lds[3][0])[v];
    pbb[v] = s0 + s1;                      // plain store -- zero atomics
  }
}

// ---------------- K6: sum chunk partials -> out ----------------
__global__ __launch_bounds__(256) void enc_reduce(
    const float* __restrict__ pb, float* __restrict__ out, int nout) {
  int idx = blockIdx.x * 256 + threadIdx.x;
  if (idx >= nout) return;
  int a = idx / 297, v = idx - a * 297;
  const float* p = pb + (size_t)a * NCHUNK * PBSTR + v;
  float s = 0.f;
  #pragma unroll 8
  for (int k = 0; k < NCHUNK; ++k) s += p[(size_t)k * PBSTR];
  out[idx] = s;
}

extern "C" void kernel_launch(void* const* d_in, const int* in_sizes, int n_in,
                              void* d_out, int out_size, void* d_ws, size_t ws_size,
                              hipStream_t stream) {
  const float* nuc  = (const float*)d_in[0];
  // d_in[1] = atom_mask (unused by reference math)
  const float* grid = (const float*)d_in[2];
  const float* wts  = (const float*)d_in[3];
  const float* nn   = (const float*)d_in[4];
  int A = in_sizes[0] / 3;
  int N = in_sizes[2] / 3;
  long long t8 = (8LL * (long long)N) / (long long)A;
  unsigned T = (unsigned)(t8 < (long long)N ? t8 : (long long)N);

  // ws: [cnt A*SLICES][b1 A][r2 A][thr A][hists A*SLICES*NB1][ghist2 A*HBINS]
  //     [pb A*SLICES*CHA*PBSTR floats][pairs uint2 ...]
  unsigned* ws     = (unsigned*)d_ws;
  unsigned* cnt    = ws;
  unsigned* b1r    = cnt + A * SLICES;
  unsigned* r2r    = b1r + A;
  unsigned* thr    = r2r + A;
  unsigned* hists  = thr + A;
  unsigned* ghist2 = hists + (size_t)A * SLICES * NB1;
  float*    pb     = (float*)(ghist2 + (size_t)A * HBINS);
  uint2*    pairs  = (uint2*)(pb + (size_t)A * SLICES * CHA * PBSTR);

  // per-slice scan range bounds the stored count -> overflow impossible
  int SCAP = (N + SLICES - 1) / SLICES;
  {
    long long head  = (long long)(((unsigned*)pairs) - ws);    // dwords
    long long avail = (long long)(ws_size / 4) - head;         // dwords
    long long need  = 2LL * SCAP * A * SLICES;                 // uint2 = 2 dwords
    if (avail > 0 && need > avail) SCAP = (int)(avail / (2LL * A * SLICES));
  }
  float* out = (float*)d_out;
  int nout = A * 297;

  enc_hist_store<<<A * SLICES,         256, 0, stream>>>(nuc, grid, N, hists, cnt,
                                                         pairs, SCAP, ghist2);
  enc_scan1     <<<A,                  256, 0, stream>>>(hists, T, b1r, r2r);
  enc_fine      <<<A * SLICES * CHF,   256, 0, stream>>>(b1r, cnt, pairs, SCAP, ghist2);
  enc_scan2     <<<A,                  256, 0, stream>>>(ghist2, b1r, r2r, thr);
  enc_accum     <<<A * SLICES * CHA,   256, 0, stream>>>(nuc, grid, wts, nn, thr, cnt,
                                                         pairs, SCAP, pb);
  enc_reduce    <<<(nout + 255) / 256, 256, 0, stream>>>(pb, out, nout);
}

// Round 11
// 65.476 us; speedup vs baseline: 2.1687x; 1.0168x over previous
//
#include <hip/hip_runtime.h>

// Encoder: per-atom top-T nearest grid points -> sum_t rbf[33] (x) (sh[9]*n*w)
// 4 dispatches (R10 lesson: ~3us/dispatch boundary; R9 lesson: redundant
// per-block reads OK iff KB-scale at high parallelism):
// K1 hist_store: full scan (float4); 256-bin clamped coarse hist (plain
//                store); (bits,idx) pair append; zeroes 512-bin fine stripe
// K2 fine      : per block: redundant coarse scan (16KB, LDS) -> b1; fine
//                hist bits[17:9] of crossing-bin pairs -> ghist2[a][512]
// K3 accum     : stage 2KB fine hist, scan -> thr (512-ULP cut, error <<
//                threshold); filter pairs, bf16 MFMA, LDS cross-wave reduce,
//                one plain 297-float store per block (no output atomics)
// K4 reduce    : sum 64 chunk-partials per atom -> out

typedef float f32x4 __attribute__((ext_vector_type(4)));
typedef int   i32x4 __attribute__((ext_vector_type(4)));

#define SLICES 16
#define NB1    256           // coarse bins (clamped)
#define NB2    512           // fine bins: bits[17:9] within crossing bin
#define CLAMP0 4000u         // bits>>18 below this (d2<~0.25) -> bin 0
#define CHA    4             // accum chunks per segment
#define CHF    2             // fine chunks per segment
#define NCHUNK (SLICES * CHA)
#define PBSTR  304           // partials row stride
#define CUT25  0x41C80000u   // __float_as_uint(25.0f) == CUTOFF^2 bits

__device__ __forceinline__ unsigned d2bits(float px, float py, float pz,
                                           float gx, float gy, float gz) {
  float dx = px - gx, dy = py - gy, dz = pz - gz;
  float d2 = __fmaf_rn(dx, dx, __fmaf_rn(dy, dy, __fmul_rn(dz, dz)));
  return __float_as_uint(d2);
}

__device__ __forceinline__ unsigned short tobf(float v) {
  return (unsigned short)((__float_as_uint(v) + 0x8000u) >> 16);
}

__device__ __forceinline__ void mfma_acc(f32x4& d, i32x4 a, i32x4 b) {
  asm("v_mfma_f32_16x16x32_bf16 %0, %1, %2, %0" : "+v"(d) : "v"(a), "v"(b));
}

// ---------------- K1: full scan -> clamped coarse hist + pairs ----------------
__global__ __launch_bounds__(256) void enc_hist_store(
    const float* __restrict__ nuc, const float* __restrict__ grid, int N,
    unsigned* __restrict__ hists, unsigned* __restrict__ cnt,
    uint2* __restrict__ pairs, int scap, unsigned* __restrict__ ghist2) {
  __shared__ unsigned lh[NB1];
  __shared__ unsigned s_cnt;
  int a = blockIdx.x / SLICES, s = blockIdx.x % SLICES;
  int tid = threadIdx.x, lane = tid & 63;
  if (tid < NB1) lh[tid] = 0;
  if (tid == 0) s_cnt = 0;
  { // zero this block's stripe of atom a's fine hist (written by K2 later)
    const int stripe = NB2 / SLICES;       // 32
    if (tid < stripe) ghist2[(size_t)a * NB2 + s * stripe + tid] = 0;
  }
  __syncthreads();

  float px = nuc[3*a+0], py = nuc[3*a+1], pz = nuc[3*a+2];
  uint2* seg = pairs + (size_t)blockIdx.x * scap;
  const float4* G4 = (const float4*)grid;
  int nq = N >> 2;
  int qper = (nq + SLICES - 1) / SLICES;
  int qlo = s * qper, qhi = min(nq, qlo + qper);

  for (int qi = qlo + tid; qi < qhi; qi += 256) {
    float4 A4 = G4[3*qi], B4 = G4[3*qi+1], C4 = G4[3*qi+2];
    float xs[4] = {A4.x, A4.w, B4.z, C4.y};
    float ys[4] = {A4.y, B4.x, B4.w, C4.z};
    float zs[4] = {A4.z, B4.y, C4.x, C4.w};
    unsigned bt[4];
    #pragma unroll
    for (int k = 0; k < 4; ++k) {
      bt[k] = d2bits(px, py, pz, xs[k], ys[k], zs[k]);
      if (bt[k] < CUT25) {
        int cb = (int)(bt[k] >> 18) - (int)CLAMP0;
        atomicAdd(&lh[cb > 0 ? cb : 0], 1u);
      }
    }
    #pragma unroll
    for (int k = 0; k < 4; ++k) {
      bool sel = bt[k] < CUT25;
      unsigned long long mm = __ballot(sel);
      if (mm) {
        int leader = __ffsll(mm) - 1;
        unsigned base = 0;
        if (lane == leader) base = atomicAdd(&s_cnt, (unsigned)__popcll(mm));
        base = __shfl(base, leader);
        if (sel) {
          unsigned pos = base + (unsigned)__popcll(mm & ((1ull << lane) - 1ull));
          if (pos < (unsigned)scap) seg[pos] = make_uint2(bt[k], (unsigned)(4*qi + k));
        }
      }
    }
  }
  if (s == SLICES - 1) {                   // scalar tail (N % 4 points)
    for (int i = 4*nq + tid; i < N; i += 256) {
      unsigned bits = d2bits(px, py, pz, grid[3*i+0], grid[3*i+1], grid[3*i+2]);
      bool sel = bits < CUT25;
      if (sel) {
        int cb = (int)(bits >> 18) - (int)CLAMP0;
        atomicAdd(&lh[cb > 0 ? cb : 0], 1u);
      }
      unsigned long long mm = __ballot(sel);
      if (mm) {
        int leader = __ffsll(mm) - 1;
        unsigned base = 0;
        if (lane == leader) base = atomicAdd(&s_cnt, (unsigned)__popcll(mm));
        base = __shfl(base, leader);
        if (sel) {
          unsigned pos = base + (unsigned)__popcll(mm & ((1ull << lane) - 1ull));
          if (pos < (unsigned)scap) seg[pos] = make_uint2(bits, (unsigned)i);
        }
      }
    }
  }
  __syncthreads();
  if (tid < NB1) hists[(size_t)blockIdx.x * NB1 + tid] = lh[tid];  // plain store
  if (tid == 0) cnt[blockIdx.x] = s_cnt;
}

// ---------------- K2: redundant coarse scan + fine hist (chunked) ----------------
__global__ __launch_bounds__(256) void enc_fine(
    const unsigned* __restrict__ hists, const unsigned* __restrict__ cnt,
    const uint2* __restrict__ pairs, int scap, unsigned T,
    unsigned* __restrict__ b1r, unsigned* __restrict__ r2r,
    unsigned* __restrict__ ghist2) {
  __shared__ unsigned lh[NB1];
  __shared__ unsigned s_bin, s_pre;
  int seg_id = blockIdx.x / CHF, c = blockIdx.x % CHF;
  int a = seg_id / SLICES, s = seg_id % SLICES;
  int tid = threadIdx.x;
  if (tid < NB1) {                         // sum the atom's 16 slice hists (16KB)
    unsigned acc = 0;
    const unsigned* base = hists + (size_t)a * SLICES * NB1 + tid;
    #pragma unroll
    for (int t = 0; t < SLICES; ++t) acc += base[(size_t)t * NB1];
    lh[tid] = acc;
  }
  if (tid == 0) { s_bin = NB1 - 1; s_pre = 0; }
  __syncthreads();
  if (tid < 64) {                          // parallel crossing-bin find
    int lane = tid, base = 4 * lane;
    unsigned h0 = lh[base], h1 = lh[base+1], h2 = lh[base+2], h3 = lh[base+3];
    unsigned ssum = h0 + h1 + h2 + h3;
    unsigned p = ssum;
    #pragma unroll
    for (int d = 1; d < 64; d <<= 1) {
      unsigned t = __shfl_up(p, d);
      if (lane >= d) p += t;
    }
    unsigned excl = p - ssum;
    if (excl < T && T <= p) {
      unsigned cum = excl;
      unsigned hh[4] = {h0, h1, h2, h3};
      #pragma unroll
      for (int k = 0; k < 4; ++k) {
        if (cum + hh[k] >= T) { s_bin = (unsigned)(base + k); s_pre = cum; break; }
        cum += hh[k];
      }
    }
  }
  __syncthreads();
  unsigned b1c = s_bin;
  if (s == 0 && c == 0 && tid == 0) { b1r[a] = s_bin; r2r[a] = T - s_pre; }

  unsigned tb1 = b1c + CLAMP0;
  int total = min((int)cnt[seg_id], scap);
  const uint2* seg = pairs + (size_t)seg_id * scap;
  unsigned* gh2 = ghist2 + (size_t)a * NB2;
  for (int i = c * 256 + tid; i < total; i += CHF * 256) {
    uint2 p = seg[i];
    unsigned cb = p.x >> 18;
    bool match = b1c ? (cb == tb1) : (cb <= CLAMP0);  // bin0 = clamped region
    if (match) atomicAdd(&gh2[(p.x >> 9) & (NB2 - 1)], 1u);
  }
}

// ---------------- K3: fine scan (2KB) + MFMA accumulation -> partials ----------------
__global__ __launch_bounds__(256, 4) void enc_accum(
    const float* __restrict__ nuc, const float* __restrict__ grid,
    const float* __restrict__ wv, const float* __restrict__ nv,
    const unsigned* __restrict__ b1r, const unsigned* __restrict__ r2r,
    const unsigned* __restrict__ ghist2, const unsigned* __restrict__ cnt,
    const uint2* __restrict__ pairs, int scap, float* __restrict__ pb) {
  __shared__ __align__(16) unsigned short lds[4][4608];  // per-wave 3456 A + 1152 B
  __shared__ unsigned lh2[NB2];
  __shared__ unsigned s_bin2;
  int seg_id = blockIdx.x / CHA, c = blockIdx.x % CHA;
  int a = seg_id / SLICES;
  int tid = threadIdx.x, lane = tid & 63, w = tid >> 6;
  unsigned short* SB = &lds[w][0];

  { // zero this wave's LDS region (covers A pad rows 33..47, B rows 9..15)
    i32x4 z = {0, 0, 0, 0};
    i32x4* zp = (i32x4*)SB;
    #pragma unroll
    for (int t = 0; t < 9; ++t) zp[lane + t * 64] = z;
  }
  { // stage atom's 512-bin fine hist (2KB)
    const unsigned* gh2 = ghist2 + (size_t)a * NB2;
    lh2[tid] = gh2[tid];
    lh2[tid + 256] = gh2[tid + 256];
  }
  if (tid == 0) s_bin2 = NB2 - 1;
  __syncthreads();
  unsigned R = r2r[a];
  if (tid < 64) {                          // two-level scan over 512 bins
    int lane2 = tid, base = 8 * lane2;
    unsigned hh[8], ssum = 0;
    #pragma unroll
    for (int k = 0; k < 8; ++k) { hh[k] = lh2[base + k]; ssum += hh[k]; }
    unsigned p = ssum;
    #pragma unroll
    for (int d = 1; d < 64; d <<= 1) {
      unsigned t = __shfl_up(p, d);
      if (lane2 >= d) p += t;
    }
    unsigned excl = p - ssum;
    if (excl < R && R <= p) {
      unsigned cum = excl;
      #pragma unroll
      for (int k = 0; k < 8; ++k) {
        if (cum + hh[k] >= R) { s_bin2 = (unsigned)(base + k); break; }
        cum += hh[k];
      }
    }
  }
  __syncthreads();
  unsigned thr = ((b1r[a] + CLAMP0) << 9) | s_bin2;   // select (bits>>9) <= thr

  float px = nuc[3*a+0], py = nuc[3*a+1], pz = nuc[3*a+2];
  int total = min((int)cnt[seg_id], scap);
  const uint2* lst = pairs + (size_t)seg_id * scap;

  f32x4 acc0 = {0,0,0,0}, acc1 = {0,0,0,0}, acc2 = {0,0,0,0};
  int m = lane & 15, q = lane >> 4;
  const float SQRT2 = 1.41421356237309515f;
  const float PIF   = 3.14159265358979323846f;
  const float S3    = 1.73205080756887729f;

  for (int jb = c * 256 + w * 64; jb < total; jb += CHA * 256) {
    int j = jb + lane;
    bool valid = j < total;
    uint2 pr = valid ? lst[j] : make_uint2(0xFFFFFFFFu, 0u);
    bool live = valid && ((pr.x >> 9) <= thr);   // stored => d2 < 25 => rn < 1
    unsigned gi = pr.y;
    if (live) {
      float gx = grid[3*gi+0], gy = grid[3*gi+1], gz = grid[3*gi+2];
      float dx = px - gx, dy = py - gy, dz = pz - gz;
      float d2 = __fmaf_rn(dx, dx, __fmaf_rn(dy, dy, dz * dz));
#if __has_builtin(__builtin_amdgcn_sqrtf)
      float rn = __builtin_amdgcn_sqrtf(d2) * 0.2f;
#else
      float rn = sqrtf(d2) * 0.2f;
#endif
      float x2 = rn * rn;
      float x6 = x2 * x2 * x2;
      float e  = __fmaf_rn(x6, __fmaf_rn(-21.f, x2, __fmaf_rn(48.f, rn, -28.f)), 1.f);
      float f  = SQRT2 * e;
      float nw = nv[gi] * wv[gi];
#if __has_builtin(__builtin_amdgcn_rcpf)
      float inv = 0.2f * __builtin_amdgcn_rcpf(rn + 1e-15f);
#else
      float inv = 0.2f / (rn + 1e-15f);
#endif
      float X = dx * inv, Y = dy * inv, Z = dz * inv;
      float r2 = __fmaf_rn(X, X, __fmaf_rn(Y, Y, Z * Z));
      // B rows: v[h] = nw * sh[h]
      SB[3456 + 0*72 + lane] = tobf(nw);
      SB[3456 + 1*72 + lane] = tobf(nw * Y);
      SB[3456 + 2*72 + lane] = tobf(nw * Z);
      SB[3456 + 3*72 + lane] = tobf(nw * X);
      SB[3456 + 4*72 + lane] = tobf(nw * S3 * X * Y);
      SB[3456 + 5*72 + lane] = tobf(nw * S3 * Y * Z);
      SB[3456 + 6*72 + lane] = tobf(nw * 0.5f * __fmaf_rn(3.f, Z * Z, -r2));
      SB[3456 + 7*72 + lane] = tobf(nw * S3 * X * Z);
      SB[3456 + 8*72 + lane] = tobf(nw * 0.5f * S3 * (X * X - Y * Y));
      // A rows: rbf[r] = sqrt2*e*[0.1, sin(k pi r), cos(k pi r)]
      float s1 = __sinf(PIF * rn), c1 = __cosf(PIF * rn);
      SB[0 * 72 + lane]  = tobf(0.1f * f);
      float sk = s1, ck = c1;
      SB[1 * 72 + lane]  = tobf(f * sk);
      SB[17 * 72 + lane] = tobf(f * ck);
      #pragma unroll
      for (int k = 2; k <= 16; ++k) {
        float sn = __fmaf_rn(sk, c1, ck * s1);
        float cn = __fmaf_rn(ck, c1, -(sk * s1));
        sk = sn; ck = cn;
        SB[k * 72 + lane]        = tobf(f * sk);
        SB[(16 + k) * 72 + lane] = tobf(f * ck);
      }
    } else {
      // zero B column -> this point contributes nothing (A may be stale)
      #pragma unroll
      for (int h = 0; h < 9; ++h) SB[3456 + h * 72 + lane] = 0;
    }
    // MFMA: A[m=r][k=p], B[k=p][n=h]; lane m=l&15, k=8*(l>>4)+j (+32 per k-group)
    #pragma unroll
    for (int g = 0; g < 2; ++g) {
      int cb = 8 * q + 32 * g;
      i32x4 bf = *(const i32x4*)&SB[3456 + m * 72 + cb];
      i32x4 a0 = *(const i32x4*)&SB[(0  + m) * 72 + cb];
      mfma_acc(acc0, a0, bf);
      i32x4 a1 = *(const i32x4*)&SB[(16 + m) * 72 + cb];
      mfma_acc(acc1, a1, bf);
      i32x4 a2 = *(const i32x4*)&SB[(32 + m) * 72 + cb];
      mfma_acc(acc2, a2, bf);
    }
  }
  // MFMA -> VALU read hazard guard
  asm volatile("s_nop 7\n\ts_nop 7" : "+v"(acc0), "+v"(acc1), "+v"(acc2));

  // cross-wave reduction in LDS (wave-private regions)
  float* redw = (float*)&lds[w][0];
  if (m < 9) {
    #pragma unroll
    for (int t = 0; t < 4; ++t) {
      int row = 4 * q + t;                 // C/D: col=lane&15, row=(lane>>4)*4+t
      redw[(row +  0) * 9 + m] = acc0[t];
      redw[(row + 16) * 9 + m] = acc1[t];
      if (row + 32 < 33) redw[(row + 32) * 9 + m] = acc2[t];
    }
  }
  __syncthreads();
  float* pbb = pb + (size_t)blockIdx.x * PBSTR;
  for (int v = tid; v < 297; v += 256) {
    float s0 = ((const float*)&lds[0][0])[v] + ((const float*)&lds[1][0])[v];
    float s1 = ((const float*)&lds[2][0])[v] + ((const float*)&lds[3][0])[v];
    pbb[v] = s0 + s1;                      // plain store -- zero atomics
  }
}

// ---------------- K4: sum chunk partials -> out ----------------
__global__ __launch_bounds__(256) void enc_reduce(
    const float* __restrict__ pb, float* __restrict__ out, int nout) {
  int idx = blockIdx.x * 256 + threadIdx.x;
  if (idx >= nout) return;
  int a = idx / 297, v = idx - a * 297;
  const float* p = pb + (size_t)a * NCHUNK * PBSTR + v;
  float s = 0.f;
  #pragma unroll 8
  for (int k = 0; k < NCHUNK; ++k) s += p[(size_t)k * PBSTR];
  out[idx] = s;
}

extern "C" void kernel_launch(void* const* d_in, const int* in_sizes, int n_in,
                              void* d_out, int out_size, void* d_ws, size_t ws_size,
                              hipStream_t stream) {
  const float* nuc  = (const float*)d_in[0];
  // d_in[1] = atom_mask (unused by reference math)
  const float* grid = (const float*)d_in[2];
  const float* wts  = (const float*)d_in[3];
  const float* nn   = (const float*)d_in[4];
  int A = in_sizes[0] / 3;
  int N = in_sizes[2] / 3;
  long long t8 = (8LL * (long long)N) / (long long)A;
  unsigned T = (unsigned)(t8 < (long long)N ? t8 : (long long)N);

  // ws: [cnt A*SLICES][b1 A][r2 A][hists A*SLICES*NB1][ghist2 A*NB2]
  //     [pb A*SLICES*CHA*PBSTR floats][pairs uint2 ...]
  unsigned* ws     = (unsigned*)d_ws;
  unsigned* cnt    = ws;
  unsigned* b1r    = cnt + A * SLICES;
  unsigned* r2r    = b1r + A;
  unsigned* hists  = r2r + A;
  unsigned* ghist2 = hists + (size_t)A * SLICES * NB1;
  float*    pb     = (float*)(ghist2 + (size_t)A * NB2);
  uint2*    pairs  = (uint2*)(pb + (size_t)A * SLICES * CHA * PBSTR);

  // per-slice scan range bounds the stored count -> overflow impossible
  int SCAP = (N + SLICES - 1) / SLICES;
  {
    long long head  = (long long)(((unsigned*)pairs) - ws);    // dwords
    long long avail = (long long)(ws_size / 4) - head;         // dwords
    long long need  = 2LL * SCAP * A * SLICES;                 // uint2 = 2 dwords
    if (avail > 0 && need > avail) SCAP = (int)(avail / (2LL * A * SLICES));
  }
  float* out = (float*)d_out;
  int nout = A * 297;

  enc_hist_store<<<A * SLICES,         256, 0, stream>>>(nuc, grid, N, hists, cnt,
                                                         pairs, SCAP, ghist2);
  enc_fine      <<<A * SLICES * CHF,   256, 0, stream>>>(hists, cnt, pairs, SCAP, T,
                                                         b1r, r2r, ghist2);
  enc_accum     <<<A * SLICES * CHA,   256, 0, stream>>>(nuc, grid, wts, nn, b1r, r2r,
                                                         ghist2, cnt, pairs, SCAP, pb);
  enc_reduce    <<<(nout + 255) / 256, 256, 0, stream>>>(pb, out, nout);
}

// Round 12
// 64.863 us; speedup vs baseline: 2.1892x; 1.0094x over previous
//
#include <hip/hip_runtime.h>

// Encoder: per-atom top-T nearest grid points -> sum_t rbf[33] (x) (sh[9]*n*w)
// R11 lesson: dispatch boundaries ~0.5us; the time is IN the kernels, and
// scan-type kernels are latency-bound -> maximize waves/CU.
// 4 dispatches:
// K1 hist_store: full scan, 2048 blocks (8/CU, 32 waves/CU); 256-bin clamped
//                coarse hist; (bits,idx) pair append; zeroes fine-hist stripe
// K2 fine      : per segment: redundant coarse scan (32KB, LDS) -> b1; fine
//                hist bits[17:9] of crossing-bin pairs -> ghist2[a][512]
// K3 accum     : stage 2KB fine hist, scan -> thr; filter pairs, bf16 MFMA,
//                LDS cross-wave reduce, one plain 297-float store per block
// K4 reduce    : sum 64 chunk-partials per atom -> out

typedef float f32x4 __attribute__((ext_vector_type(4)));
typedef int   i32x4 __attribute__((ext_vector_type(4)));

#define SLICES 32
#define NB1    256           // coarse bins (clamped)
#define NB2    512           // fine bins: bits[17:9] within crossing bin
#define CLAMP0 4000u         // bits>>18 below this (d2<~0.25) -> bin 0
#define CHA    2             // accum chunks per segment
#define NCHUNK (SLICES * CHA)
#define PBSTR  304           // partials row stride
#define CUT25  0x41C80000u   // __float_as_uint(25.0f) == CUTOFF^2 bits

__device__ __forceinline__ unsigned d2bits(float px, float py, float pz,
                                           float gx, float gy, float gz) {
  float dx = px - gx, dy = py - gy, dz = pz - gz;
  float d2 = __fmaf_rn(dx, dx, __fmaf_rn(dy, dy, __fmul_rn(dz, dz)));
  return __float_as_uint(d2);
}

__device__ __forceinline__ unsigned short tobf(float v) {
  return (unsigned short)((__float_as_uint(v) + 0x8000u) >> 16);
}

__device__ __forceinline__ void mfma_acc(f32x4& d, i32x4 a, i32x4 b) {
  asm("v_mfma_f32_16x16x32_bf16 %0, %1, %2, %0" : "+v"(d) : "v"(a), "v"(b));
}

// ---------------- K1: full scan -> clamped coarse hist + pairs ----------------
__global__ __launch_bounds__(256, 8) void enc_hist_store(
    const float* __restrict__ nuc, const float* __restrict__ grid, int N,
    unsigned* __restrict__ hists, unsigned* __restrict__ cnt,
    uint2* __restrict__ pairs, int scap, unsigned* __restrict__ ghist2) {
  __shared__ unsigned lh[NB1];
  __shared__ unsigned s_cnt;
  int a = blockIdx.x / SLICES, s = blockIdx.x % SLICES;
  int tid = threadIdx.x, lane = tid & 63;
  if (tid < NB1) lh[tid] = 0;
  if (tid == 0) s_cnt = 0;
  { // zero this block's stripe of atom a's fine hist (written by K2 later)
    const int stripe = NB2 / SLICES;       // 16
    if (tid < stripe) ghist2[(size_t)a * NB2 + s * stripe + tid] = 0;
  }
  __syncthreads();

  float px = nuc[3*a+0], py = nuc[3*a+1], pz = nuc[3*a+2];
  uint2* seg = pairs + (size_t)blockIdx.x * scap;
  const float4* G4 = (const float4*)grid;
  int nq = N >> 2;
  int qper = (nq + SLICES - 1) / SLICES;
  int qlo = s * qper, qhi = min(nq, qlo + qper);

  for (int qi = qlo + tid; qi < qhi; qi += 256) {
    float4 A4 = G4[3*qi], B4 = G4[3*qi+1], C4 = G4[3*qi+2];
    float xs[4] = {A4.x, A4.w, B4.z, C4.y};
    float ys[4] = {A4.y, B4.x, B4.w, C4.z};
    float zs[4] = {A4.z, B4.y, C4.x, C4.w};
    unsigned bt[4];
    #pragma unroll
    for (int k = 0; k < 4; ++k) {
      bt[k] = d2bits(px, py, pz, xs[k], ys[k], zs[k]);
      if (bt[k] < CUT25) {
        int cb = (int)(bt[k] >> 18) - (int)CLAMP0;
        atomicAdd(&lh[cb > 0 ? cb : 0], 1u);
      }
    }
    #pragma unroll
    for (int k = 0; k < 4; ++k) {
      bool sel = bt[k] < CUT25;
      unsigned long long mm = __ballot(sel);
      if (mm) {
        int leader = __ffsll(mm) - 1;
        unsigned base = 0;
        if (lane == leader) base = atomicAdd(&s_cnt, (unsigned)__popcll(mm));
        base = __shfl(base, leader);
        if (sel) {
          unsigned pos = base + (unsigned)__popcll(mm & ((1ull << lane) - 1ull));
          if (pos < (unsigned)scap) seg[pos] = make_uint2(bt[k], (unsigned)(4*qi + k));
        }
      }
    }
  }
  if (s == SLICES - 1) {                   // scalar tail (N % 4 points)
    for (int i = 4*nq + tid; i < N; i += 256) {
      unsigned bits = d2bits(px, py, pz, grid[3*i+0], grid[3*i+1], grid[3*i+2]);
      bool sel = bits < CUT25;
      if (sel) {
        int cb = (int)(bits >> 18) - (int)CLAMP0;
        atomicAdd(&lh[cb > 0 ? cb : 0], 1u);
      }
      unsigned long long mm = __ballot(sel);
      if (mm) {
        int leader = __ffsll(mm) - 1;
        unsigned base = 0;
        if (lane == leader) base = atomicAdd(&s_cnt, (unsigned)__popcll(mm));
        base = __shfl(base, leader);
        if (sel) {
          unsigned pos = base + (unsigned)__popcll(mm & ((1ull << lane) - 1ull));
          if (pos < (unsigned)scap) seg[pos] = make_uint2(bits, (unsigned)i);
        }
      }
    }
  }
  __syncthreads();
  if (tid < NB1) hists[(size_t)blockIdx.x * NB1 + tid] = lh[tid];  // plain store
  if (tid == 0) cnt[blockIdx.x] = s_cnt;
}

// ---------------- K2: redundant coarse scan + fine hist (per segment) ----------------
__global__ __launch_bounds__(256, 8) void enc_fine(
    const unsigned* __restrict__ hists, const unsigned* __restrict__ cnt,
    const uint2* __restrict__ pairs, int scap, unsigned T,
    unsigned* __restrict__ b1r, unsigned* __restrict__ r2r,
    unsigned* __restrict__ ghist2) {
  __shared__ unsigned lh[NB1];
  __shared__ unsigned s_bin, s_pre;
  int seg_id = blockIdx.x;
  int a = seg_id / SLICES, s = seg_id % SLICES;
  int tid = threadIdx.x;
  if (tid < NB1) {                         // sum the atom's 32 slice hists (32KB)
    unsigned acc = 0;
    const unsigned* base = hists + (size_t)a * SLICES * NB1 + tid;
    #pragma unroll 8
    for (int t = 0; t < SLICES; ++t) acc += base[(size_t)t * NB1];
    lh[tid] = acc;
  }
  if (tid == 0) { s_bin = NB1 - 1; s_pre = 0; }
  __syncthreads();
  if (tid < 64) {                          // parallel crossing-bin find
    int lane = tid, base = 4 * lane;
    unsigned h0 = lh[base], h1 = lh[base+1], h2 = lh[base+2], h3 = lh[base+3];
    unsigned ssum = h0 + h1 + h2 + h3;
    unsigned p = ssum;
    #pragma unroll
    for (int d = 1; d < 64; d <<= 1) {
      unsigned t = __shfl_up(p, d);
      if (lane >= d) p += t;
    }
    unsigned excl = p - ssum;
    if (excl < T && T <= p) {
      unsigned cum = excl;
      unsigned hh[4] = {h0, h1, h2, h3};
      #pragma unroll
      for (int k = 0; k < 4; ++k) {
        if (cum + hh[k] >= T) { s_bin = (unsigned)(base + k); s_pre = cum; break; }
        cum += hh[k];
      }
    }
  }
  __syncthreads();
  unsigned b1c = s_bin;
  if (s == 0 && tid == 0) { b1r[a] = s_bin; r2r[a] = T - s_pre; }

  unsigned tb1 = b1c + CLAMP0;
  int total = min((int)cnt[seg_id], scap);
  const uint2* seg = pairs + (size_t)seg_id * scap;
  unsigned* gh2 = ghist2 + (size_t)a * NB2;
  for (int i = tid; i < total; i += 256) {
    uint2 p = seg[i];
    unsigned cb = p.x >> 18;
    bool match = b1c ? (cb == tb1) : (cb <= CLAMP0);  // bin0 = clamped region
    if (match) atomicAdd(&gh2[(p.x >> 9) & (NB2 - 1)], 1u);
  }
}

// ---------------- K3: fine scan (2KB) + MFMA accumulation -> partials ----------------
__global__ __launch_bounds__(256, 4) void enc_accum(
    const float* __restrict__ nuc, const float* __restrict__ grid,
    const float* __restrict__ wv, const float* __restrict__ nv,
    const unsigned* __restrict__ b1r, const unsigned* __restrict__ r2r,
    const unsigned* __restrict__ ghist2, const unsigned* __restrict__ cnt,
    const uint2* __restrict__ pairs, int scap, float* __restrict__ pb) {
  __shared__ __align__(16) unsigned short lds[4][4608];  // per-wave 3456 A + 1152 B
  __shared__ unsigned lh2[NB2];
  __shared__ unsigned s_bin2;
  int seg_id = blockIdx.x / CHA, c = blockIdx.x % CHA;
  int a = seg_id / SLICES;
  int tid = threadIdx.x, lane = tid & 63, w = tid >> 6;
  unsigned short* SB = &lds[w][0];

  { // zero this wave's LDS region (covers A pad rows 33..47, B rows 9..15)
    i32x4 z = {0, 0, 0, 0};
    i32x4* zp = (i32x4*)SB;
    #pragma unroll
    for (int t = 0; t < 9; ++t) zp[lane + t * 64] = z;
  }
  { // stage atom's 512-bin fine hist (2KB)
    const unsigned* gh2 = ghist2 + (size_t)a * NB2;
    lh2[tid] = gh2[tid];
    lh2[tid + 256] = gh2[tid + 256];
  }
  if (tid == 0) s_bin2 = NB2 - 1;
  __syncthreads();
  unsigned R = r2r[a];
  if (tid < 64) {                          // two-level scan over 512 bins
    int lane2 = tid, base = 8 * lane2;
    unsigned hh[8], ssum = 0;
    #pragma unroll
    for (int k = 0; k < 8; ++k) { hh[k] = lh2[base + k]; ssum += hh[k]; }
    unsigned p = ssum;
    #pragma unroll
    for (int d = 1; d < 64; d <<= 1) {
      unsigned t = __shfl_up(p, d);
      if (lane2 >= d) p += t;
    }
    unsigned excl = p - ssum;
    if (excl < R && R <= p) {
      unsigned cum = excl;
      #pragma unroll
      for (int k = 0; k < 8; ++k) {
        if (cum + hh[k] >= R) { s_bin2 = (unsigned)(base + k); break; }
        cum += hh[k];
      }
    }
  }
  __syncthreads();
  unsigned thr = ((b1r[a] + CLAMP0) << 9) | s_bin2;   // select (bits>>9) <= thr

  float px = nuc[3*a+0], py = nuc[3*a+1], pz = nuc[3*a+2];
  int total = min((int)cnt[seg_id], scap);
  const uint2* lst = pairs + (size_t)seg_id * scap;

  f32x4 acc0 = {0,0,0,0}, acc1 = {0,0,0,0}, acc2 = {0,0,0,0};
  int m = lane & 15, q = lane >> 4;
  const float SQRT2 = 1.41421356237309515f;
  const float PIF   = 3.14159265358979323846f;
  const float S3    = 1.73205080756887729f;

  for (int jb = c * 256 + w * 64; jb < total; jb += CHA * 256) {
    int j = jb + lane;
    bool valid = j < total;
    uint2 pr = valid ? lst[j] : make_uint2(0xFFFFFFFFu, 0u);
    bool live = valid && ((pr.x >> 9) <= thr);   // stored => d2 < 25 => rn < 1
    unsigned gi = pr.y;
    if (live) {
      float gx = grid[3*gi+0], gy = grid[3*gi+1], gz = grid[3*gi+2];
      float dx = px - gx, dy = py - gy, dz = pz - gz;
      float d2 = __fmaf_rn(dx, dx, __fmaf_rn(dy, dy, dz * dz));
#if __has_builtin(__builtin_amdgcn_sqrtf)
      float rn = __builtin_amdgcn_sqrtf(d2) * 0.2f;
#else
      float rn = sqrtf(d2) * 0.2f;
#endif
      float x2 = rn * rn;
      float x6 = x2 * x2 * x2;
      float e  = __fmaf_rn(x6, __fmaf_rn(-21.f, x2, __fmaf_rn(48.f, rn, -28.f)), 1.f);
      float f  = SQRT2 * e;
      float nw = nv[gi] * wv[gi];
#if __has_builtin(__builtin_amdgcn_rcpf)
      float inv = 0.2f * __builtin_amdgcn_rcpf(rn + 1e-15f);
#else
      float inv = 0.2f / (rn + 1e-15f);
#endif
      float X = dx * inv, Y = dy * inv, Z = dz * inv;
      float r2 = __fmaf_rn(X, X, __fmaf_rn(Y, Y, Z * Z));
      // B rows: v[h] = nw * sh[h]
      SB[3456 + 0*72 + lane] = tobf(nw);
      SB[3456 + 1*72 + lane] = tobf(nw * Y);
      SB[3456 + 2*72 + lane] = tobf(nw * Z);
      SB[3456 + 3*72 + lane] = tobf(nw * X);
      SB[3456 + 4*72 + lane] = tobf(nw * S3 * X * Y);
      SB[3456 + 5*72 + lane] = tobf(nw * S3 * Y * Z);
      SB[3456 + 6*72 + lane] = tobf(nw * 0.5f * __fmaf_rn(3.f, Z * Z, -r2));
      SB[3456 + 7*72 + lane] = tobf(nw * S3 * X * Z);
      SB[3456 + 8*72 + lane] = tobf(nw * 0.5f * S3 * (X * X - Y * Y));
      // A rows: rbf[r] = sqrt2*e*[0.1, sin(k pi r), cos(k pi r)]
      float s1 = __sinf(PIF * rn), c1 = __cosf(PIF * rn);
      SB[0 * 72 + lane]  = tobf(0.1f * f);
      float sk = s1, ck = c1;
      SB[1 * 72 + lane]  = tobf(f * sk);
      SB[17 * 72 + lane] = tobf(f * ck);
      #pragma unroll
      for (int k = 2; k <= 16; ++k) {
        float sn = __fmaf_rn(sk, c1, ck * s1);
        float cn = __fmaf_rn(ck, c1, -(sk * s1));
        sk = sn; ck = cn;
        SB[k * 72 + lane]        = tobf(f * sk);
        SB[(16 + k) * 72 + lane] = tobf(f * ck);
      }
    } else {
      // zero B column -> this point contributes nothing (A may be stale)
      #pragma unroll
      for (int h = 0; h < 9; ++h) SB[3456 + h * 72 + lane] = 0;
    }
    // MFMA: A[m=r][k=p], B[k=p][n=h]; lane m=l&15, k=8*(l>>4)+j (+32 per k-group)
    #pragma unroll
    for (int g = 0; g < 2; ++g) {
      int cb = 8 * q + 32 * g;
      i32x4 bf = *(const i32x4*)&SB[3456 + m * 72 + cb];
      i32x4 a0 = *(const i32x4*)&SB[(0  + m) * 72 + cb];
      mfma_acc(acc0, a0, bf);
      i32x4 a1 = *(const i32x4*)&SB[(16 + m) * 72 + cb];
      mfma_acc(acc1, a1, bf);
      i32x4 a2 = *(const i32x4*)&SB[(32 + m) * 72 + cb];
      mfma_acc(acc2, a2, bf);
    }
  }
  // MFMA -> VALU read hazard guard
  asm volatile("s_nop 7\n\ts_nop 7" : "+v"(acc0), "+v"(acc1), "+v"(acc2));

  // cross-wave reduction in LDS (wave-private regions)
  float* redw = (float*)&lds[w][0];
  if (m < 9) {
    #pragma unroll
    for (int t = 0; t < 4; ++t) {
      int row = 4 * q + t;                 // C/D: col=lane&15, row=(lane>>4)*4+t
      redw[(row +  0) * 9 + m] = acc0[t];
      redw[(row + 16) * 9 + m] = acc1[t];
      if (row + 32 < 33) redw[(row + 32) * 9 + m] = acc2[t];
    }
  }
  __syncthreads();
  float* pbb = pb + (size_t)blockIdx.x * PBSTR;
  for (int v = tid; v < 297; v += 256) {
    float s0 = ((const float*)&lds[0][0])[v] + ((const float*)&lds[1][0])[v];
    float s1 = ((const float*)&lds[2][0])[v] + ((const float*)&lds[3][0])[v];
    pbb[v] = s0 + s1;                      // plain store -- zero atomics
  }
}

// ---------------- K4: sum chunk partials -> out ----------------
__global__ __launch_bounds__(256) void enc_reduce(
    const float* __restrict__ pb, float* __restrict__ out, int nout) {
  int idx = blockIdx.x * 256 + threadIdx.x;
  if (idx >= nout) return;
  int a = idx / 297, v = idx - a * 297;
  const float* p = pb + (size_t)a * NCHUNK * PBSTR + v;
  float s = 0.f;
  #pragma unroll 8
  for (int k = 0; k < NCHUNK; ++k) s += p[(size_t)k * PBSTR];
  out[idx] = s;
}

extern "C" void kernel_launch(void* const* d_in, const int* in_sizes, int n_in,
                              void* d_out, int out_size, void* d_ws, size_t ws_size,
                              hipStream_t stream) {
  const float* nuc  = (const float*)d_in[0];
  // d_in[1] = atom_mask (unused by reference math)
  const float* grid = (const float*)d_in[2];
  const float* wts  = (const float*)d_in[3];
  const float* nn   = (const float*)d_in[4];
  int A = in_sizes[0] / 3;
  int N = in_sizes[2] / 3;
  long long t8 = (8LL * (long long)N) / (long long)A;
  unsigned T = (unsigned)(t8 < (long long)N ? t8 : (long long)N);

  // ws: [cnt A*SLICES][b1 A][r2 A][hists A*SLICES*NB1][ghist2 A*NB2]
  //     [pb A*SLICES*CHA*PBSTR floats][pairs uint2 ...]
  unsigned* ws     = (unsigned*)d_ws;
  unsigned* cnt    = ws;
  unsigned* b1r    = cnt + A * SLICES;
  unsigned* r2r    = b1r + A;
  unsigned* hists  = r2r + A;
  unsigned* ghist2 = hists + (size_t)A * SLICES * NB1;
  float*    pb     = (float*)(ghist2 + (size_t)A * NB2);
  uint2*    pairs  = (uint2*)(pb + (size_t)A * SLICES * CHA * PBSTR);

  // per-slice quad range bounds the stored count -> overflow impossible
  int nq   = N >> 2;
  int qper = (nq + SLICES - 1) / SLICES;
  int SCAP = qper * 4 + 4;
  {
    long long head  = (long long)(((unsigned*)pairs) - ws);    // dwords
    long long avail = (long long)(ws_size / 4) - head;         // dwords
    long long need  = 2LL * SCAP * A * SLICES;                 // uint2 = 2 dwords
    if (avail > 0 && need > avail) SCAP = (int)(avail / (2LL * A * SLICES));
  }
  float* out = (float*)d_out;
  int nout = A * 297;

  enc_hist_store<<<A * SLICES,         256, 0, stream>>>(nuc, grid, N, hists, cnt,
                                                         pairs, SCAP, ghist2);
  enc_fine      <<<A * SLICES,         256, 0, stream>>>(hists, cnt, pairs, SCAP, T,
                                                         b1r, r2r, ghist2);
  enc_accum     <<<A * SLICES * CHA,   256, 0, stream>>>(nuc, grid, wts, nn, b1r, r2r,
                                                         ghist2, cnt, pairs, SCAP, pb);
  enc_reduce    <<<(nout + 255) / 256, 256, 0, stream>>>(pb, out, nout);
}